// Round 6
// baseline (646.358 us; speedup 1.0000x reference)
//
#include <hip/hip_runtime.h>
#include <hip/hip_bf16.h>
#include <math.h>

// Problem constants (match reference)
#define NNODES 100000
#define NPAD   100032        // padded to multiple of 64 for guard-free GEMM
#define IN_DIM 128
#define HID 128
#define HEADS 2
#define F2 256               // HEADS*HID
#define NEDGES 800000
#define ETOT 900000          // NEDGES + NNODES self-loops
#define NEG_SLOPE 0.2f
#define HIST_BLOCKS 3516     // (ETOT+255)/256
#define ALPHA_BLOCKS 25000   // NNODES/4 waves
#define SCAN_CH 98           // ceil(NNODES/1024)

typedef unsigned int uint;
typedef unsigned short ushort;
typedef __attribute__((ext_vector_type(8))) short short8;
typedef __attribute__((ext_vector_type(4))) float floatx4;

__device__ __forceinline__ ushort f2bf(float f) {
    uint u = __builtin_bit_cast(uint, f);
    u += 0x7fffu + ((u >> 16) & 1u);       // round-to-nearest-even
    return (ushort)(u >> 16);
}
__device__ __forceinline__ float bf2f(uint u16) {
    return __builtin_bit_cast(float, u16 << 16);
}

// ---------------------------------------------------------------------------
// setup1: histogram (blocks [0,HIST_BLOCKS)) merged with weight prep.
// prep: W1^T, W2^T (bf16) + fused post_mp weights + layer-1 projection
// vectors va[k] = (W1h0@a_src1h0, W1h1@a_src1h1, W1h0@a_dst1h0, W1h1@a_dst1h1)
// ---------------------------------------------------------------------------
__global__ __launch_bounds__(256) void setup1_kernel(const int* __restrict__ ei,
                                                     int* __restrict__ deg,
                                                     const float* __restrict__ W1,
                                                     ushort* __restrict__ W1t,
                                                     const float* __restrict__ W2,
                                                     ushort* __restrict__ W2t,
                                                     const float* __restrict__ Wp1,
                                                     const float* __restrict__ bp1,
                                                     const float* __restrict__ Wp2,
                                                     const float* __restrict__ bp2,
                                                     float2* __restrict__ Wf,
                                                     float* __restrict__ bfv,
                                                     const float* __restrict__ a_src1,
                                                     const float* __restrict__ a_dst1,
                                                     float* __restrict__ va) {
    int b = blockIdx.x, t = threadIdx.x;
    if (b < HIST_BLOCKS) {               // histogram
        int i = b * 256 + t;
        if (i >= ETOT) return;
        int dst = (i < NEDGES) ? ei[NEDGES + i] : (i - NEDGES);
        atomicAdd(&deg[dst], 1);
        return;
    }
    int b2 = b - HIST_BLOCKS;
    if (b2 < 128) {                      // W1t[n][k] = W1[k][n], K=128, N=256
        int i = b2 * 256 + t;
        int n = i >> 7, k = i & 127;
        W1t[n * 128 + k] = f2bf(W1[k * 256 + n]);
    } else if (b2 < 384) {               // W2t[n][k] = W2[k][n], K=256, N=256
        int i = (b2 - 128) * 256 + t;
        int n = i >> 8, k = i & 255;
        W2t[n * 256 + k] = f2bf(W2[k * 256 + n]);
    } else if (b2 == 384) {              // Wf[k] = Wp1[k][:] @ Wp2 ; bfv
        float s0 = 0.f, s1 = 0.f;
        for (int m = 0; m < 128; m++) {
            float w = Wp1[t * 128 + m];
            s0 += w * Wp2[2 * m];
            s1 += w * Wp2[2 * m + 1];
        }
        Wf[t] = make_float2(s0, s1);
        if (t < 2) {
            float bb = bp2[t];
            for (int m = 0; m < 128; m++) bb += bp1[m] * Wp2[2 * m + t];
            bfv[t] = bb;
        }
    } else {                             // va projection vectors (f32, exact)
        int k = t & 127, sel = t >> 7;   // sel 0 = src, 1 = dst
        const float* av = sel ? a_dst1 : a_src1;   // [2][128]
        float s0 = 0.f, s1 = 0.f;
        for (int j = 0; j < 128; j++) {
            s0 += W1[k * 256 + j]       * av[j];
            s1 += W1[k * 256 + 128 + j] * av[128 + j];
        }
        va[k * 4 + sel * 2 + 0] = s0;
        va[k * 4 + sel * 2 + 1] = s1;
    }
}

// ---------------------------------------------------------------------------
// scan_one: single-workgroup exclusive scan of deg -> row_start + cursor.
// 1024 threads x 98 contiguous elems, two-pass (sum, then write prefixes).
// Replaces scan1+scan_fix (2 dispatches -> 1).
// ---------------------------------------------------------------------------
__global__ __launch_bounds__(1024) void scan_one_kernel(const int* __restrict__ deg,
                                                        int* __restrict__ row_start,
                                                        int* __restrict__ cursor) {
    __shared__ int sh[1024];
    int t = threadIdx.x;
    int base = t * SCAN_CH;
    int lim = base + SCAN_CH < NNODES ? base + SCAN_CH : NNODES;
    int sum = 0;
    for (int i = base; i < lim; i++) sum += deg[i];
    sh[t] = sum;
    __syncthreads();
    for (int off = 1; off < 1024; off <<= 1) {   // Hillis-Steele inclusive
        int v = (t >= off) ? sh[t - off] : 0;
        __syncthreads();
        sh[t] += v;
        __syncthreads();
    }
    int run = sh[t] - sum;                       // exclusive chunk prefix
    for (int i = base; i < lim; i++) {
        row_start[i] = run;
        cursor[i] = run;
        run += deg[i];
    }
    if (t == 1023) row_start[NNODES] = ETOT;
}

// ---------------------------------------------------------------------------
// scatter_alpha: blocks [0,ALPHA_BLOCKS) = alpha_x (per node: xb bf16 pack +
// layer-1 logits as1/ad1 = x.va); blocks [ALPHA_BLOCKS,..) = CSR scatter.
// Independent latency-bound work overlapped in one dispatch.
// ---------------------------------------------------------------------------
__global__ __launch_bounds__(256) void scatter_alpha_kernel(const int* __restrict__ ei,
                                                            int* __restrict__ cursor,
                                                            int* __restrict__ csr_src,
                                                            const float* __restrict__ x,
                                                            const float4* __restrict__ va4,
                                                            uint* __restrict__ xb,
                                                            float2* __restrict__ as_,
                                                            float2* __restrict__ ad_) {
    int b = blockIdx.x;
    if (b < ALPHA_BLOCKS) {              // alpha_x path
        int wave = threadIdx.x >> 6, lane = threadIdx.x & 63;
        int n = b * 4 + wave;
        if (n >= NNODES) return;
        float2 xv = *reinterpret_cast<const float2*>(x + (size_t)n * 128 + lane * 2);
        xb[(size_t)n * 64 + lane] = (uint)f2bf(xv.x) | ((uint)f2bf(xv.y) << 16);
        float4 v0 = va4[2 * lane];       // feat k = 2*lane: (src0,src1,dst0,dst1)
        float4 v1 = va4[2 * lane + 1];   // feat k = 2*lane+1
        float ss0 = xv.x * v0.x + xv.y * v1.x;
        float ss1 = xv.x * v0.y + xv.y * v1.y;
        float sd0 = xv.x * v0.z + xv.y * v1.z;
        float sd1 = xv.x * v0.w + xv.y * v1.w;
#pragma unroll
        for (int o = 32; o; o >>= 1) {
            ss0 += __shfl_xor(ss0, o);
            ss1 += __shfl_xor(ss1, o);
            sd0 += __shfl_xor(sd0, o);
            sd1 += __shfl_xor(sd1, o);
        }
        if (lane == 0) {
            as_[n] = make_float2(ss0, ss1);
            ad_[n] = make_float2(sd0, sd1);
        }
        return;
    }
    int i = (b - ALPHA_BLOCKS) * 256 + threadIdx.x;   // scatter path
    if (i >= ETOT) return;
    int src, dst;
    if (i < NEDGES) { src = ei[i]; dst = ei[NEDGES + i]; }
    else            { src = i - NEDGES; dst = src; }
    int pos = atomicAdd(&cursor[dst], 1);
    csr_src[pos] = src;
}

// ---------------------------------------------------------------------------
// layer-1 gather in INPUT space: 256B bf16 rows (xb). 4-way quad split.
// Output g1 row = [head0 128 bf16 | head1 128 bf16] (512B). No bias/relu
// (moved to fused GEMM phase-1 epilogue). Full-occupancy (no LDS, 24 VGPR) —
// R5 proved merging this into the GEMM kernel kills it via occupancy.
// ---------------------------------------------------------------------------
__global__ __launch_bounds__(256) void gather1_kernel(const uint* __restrict__ xb,
                                                      const int* __restrict__ row_start,
                                                      const int* __restrict__ csr_src,
                                                      const float2* __restrict__ as_,
                                                      const float2* __restrict__ ad_,
                                                      ushort* __restrict__ g1) {
    int wave = threadIdx.x >> 6, lane = threadIdx.x & 63;
    int n = blockIdx.x * 4 + wave;
    if (n >= NNODES) return;
    int beg = __builtin_amdgcn_readfirstlane(row_start[n]);
    int end = __builtin_amdgcn_readfirstlane(row_start[n + 1]);
    int fl = lane & 15;            // feature lane: bytes fl*16 .. fl*16+15
    int q  = lane >> 4;            // quad: edge base+q
    float2 ad = ad_[n];
    float ad0 = ad.x, ad1 = ad.y;

    float a00 = 0.f, a01 = 0.f, a02 = 0.f, a03 = 0.f;
    float a04 = 0.f, a05 = 0.f, a06 = 0.f, a07 = 0.f;   // head0
    float a10 = 0.f, a11 = 0.f, a12 = 0.f, a13 = 0.f;
    float a14 = 0.f, a15 = 0.f, a16 = 0.f, a17 = 0.f;   // head1
    float aden0 = 0.f, aden1 = 0.f;
    const char* hbase = (const char*)xb;
    uint laneoff = (uint)fl * 16u;
    int last = end - 1;

    for (int j = beg; j < end; j += 4) {
        int e = j + q;
        int c = e < end ? e : last;
        int s = csr_src[c];
        uint4 h = *(const uint4*)(hbase + (size_t)(((uint)s << 8) + laneoff));
        float2 qv = as_[s];
        float l0 = qv.x + ad0; l0 = fmaxf(l0, NEG_SLOPE * l0);
        float l1 = qv.y + ad1; l1 = fmaxf(l1, NEG_SLOPE * l1);
        float w0 = (e < end) ? __expf(l0) : 0.f;
        float w1 = (e < end) ? __expf(l1) : 0.f;
        aden0 += w0; aden1 += w1;
        float f0 = bf2f(h.x & 0xffffu), f1 = bf2f(h.x >> 16);
        float f2 = bf2f(h.y & 0xffffu), f3 = bf2f(h.y >> 16);
        float f4 = bf2f(h.z & 0xffffu), f5 = bf2f(h.z >> 16);
        float f6 = bf2f(h.w & 0xffffu), f7 = bf2f(h.w >> 16);
        a00 += w0 * f0; a01 += w0 * f1; a02 += w0 * f2; a03 += w0 * f3;
        a04 += w0 * f4; a05 += w0 * f5; a06 += w0 * f6; a07 += w0 * f7;
        a10 += w1 * f0; a11 += w1 * f1; a12 += w1 * f2; a13 += w1 * f3;
        a14 += w1 * f4; a15 += w1 * f5; a16 += w1 * f6; a17 += w1 * f7;
    }

    // cross-quad reduction (xor 16 then 32 -> every lane holds totals)
#pragma unroll
    for (int o = 16; o <= 32; o <<= 1) {
        aden0 += __shfl_xor(aden0, o); aden1 += __shfl_xor(aden1, o);
        a00 += __shfl_xor(a00, o); a01 += __shfl_xor(a01, o);
        a02 += __shfl_xor(a02, o); a03 += __shfl_xor(a03, o);
        a04 += __shfl_xor(a04, o); a05 += __shfl_xor(a05, o);
        a06 += __shfl_xor(a06, o); a07 += __shfl_xor(a07, o);
        a10 += __shfl_xor(a10, o); a11 += __shfl_xor(a11, o);
        a12 += __shfl_xor(a12, o); a13 += __shfl_xor(a13, o);
        a14 += __shfl_xor(a14, o); a15 += __shfl_xor(a15, o);
        a16 += __shfl_xor(a16, o); a17 += __shfl_xor(a17, o);
    }
    float inv0 = 1.f / (aden0 + 1e-16f);
    float inv1 = 1.f / (aden1 + 1e-16f);
    if (q == 0) {                  // head0 bytes [0,256)
        uint4 pk;
        pk.x = (uint)f2bf(a00 * inv0) | ((uint)f2bf(a01 * inv0) << 16);
        pk.y = (uint)f2bf(a02 * inv0) | ((uint)f2bf(a03 * inv0) << 16);
        pk.z = (uint)f2bf(a04 * inv0) | ((uint)f2bf(a05 * inv0) << 16);
        pk.w = (uint)f2bf(a06 * inv0) | ((uint)f2bf(a07 * inv0) << 16);
        *(uint4*)((char*)g1 + (size_t)n * 512 + fl * 16) = pk;
    } else if (q == 1) {           // head1 bytes [256,512)
        uint4 pk;
        pk.x = (uint)f2bf(a10 * inv1) | ((uint)f2bf(a11 * inv1) << 16);
        pk.y = (uint)f2bf(a12 * inv1) | ((uint)f2bf(a13 * inv1) << 16);
        pk.z = (uint)f2bf(a14 * inv1) | ((uint)f2bf(a15 * inv1) << 16);
        pk.w = (uint)f2bf(a16 * inv1) | ((uint)f2bf(a17 * inv1) << 16);
        *(uint4*)((char*)g1 + (size_t)n * 512 + 256 + fl * 16) = pk;
    }
}

// ---------------------------------------------------------------------------
// FUSED double GEMM per 64-row block (R4-proven):
//   phase 1 (per head h): out1[:,h*128:] = relu(g1[:,h*128:] @ W1_h + b1_h)
//            -> stored in LDS O1[64][264] as bf16 (never touches HBM)
//   phase 2 (per col-half y): h2[:, y*128:] = out1 @ W2[:, y*128:]
//            A-fragments read DIRECTLY from O1 (zero A staging),
//            epilogue writes h2 + layer-2 attention logits as2/ad2.
// ---------------------------------------------------------------------------
__global__ __launch_bounds__(256) void mfma_gemm_fused(const ushort* __restrict__ A,
                                                       const ushort* __restrict__ B1t,
                                                       const float* __restrict__ bias1,
                                                       const ushort* __restrict__ B2t,
                                                       ushort* __restrict__ C,
                                                       float* __restrict__ as_f,
                                                       float* __restrict__ ad_f,
                                                       const float* __restrict__ aS,
                                                       const float* __restrict__ aD) {
    __shared__ ushort As[64][40];
    __shared__ ushort Bs[128][40];
    __shared__ ushort O1[64][264];   // row stride 528B: 16B-aligned
    int t = threadIdx.x;
    int wave = t >> 6, lane = t & 63;
    int quad = lane >> 4, l16 = lane & 15;
    size_t rowBase = (size_t)blockIdx.x * 64;
    int ar = t >> 2, ac = (t & 3) * 8;
    union { uint4 u; short8 s; } afr, bfr;

    // ---- phase 1: two heads, K=128 each ----
    for (int h = 0; h < 2; h++) {
        floatx4 acc[8];
#pragma unroll
        for (int i = 0; i < 8; i++) acc[i] = (floatx4){0.f, 0.f, 0.f, 0.f};
        const ushort* Ap  = A + (rowBase + ar) * 256 + h * 128 + ac;  // lda=256
        const ushort* Bp0 = B1t + (size_t)(h * 128 + ar) * 128 + ac;
        const ushort* Bp1 = Bp0 + (size_t)64 * 128;

        for (int k0 = 0; k0 < 128; k0 += 32) {
            uint4 av  = *reinterpret_cast<const uint4*>(Ap + k0);
            uint4 b0  = *reinterpret_cast<const uint4*>(Bp0 + k0);
            uint4 b1v = *reinterpret_cast<const uint4*>(Bp1 + k0);
            __syncthreads();             // prior MFMAs / O1 stores done
            *reinterpret_cast<uint4*>(&As[ar][ac])      = av;
            *reinterpret_cast<uint4*>(&Bs[ar][ac])      = b0;
            *reinterpret_cast<uint4*>(&Bs[64 + ar][ac]) = b1v;
            __syncthreads();
            afr.u = *reinterpret_cast<const uint4*>(&As[wave * 16 + l16][quad * 8]);
#pragma unroll
            for (int nt = 0; nt < 8; nt++) {
                bfr.u = *reinterpret_cast<const uint4*>(&Bs[nt * 16 + l16][quad * 8]);
                acc[nt] = __builtin_amdgcn_mfma_f32_16x16x32_bf16(afr.s, bfr.s, acc[nt], 0, 0, 0);
            }
        }
        // epilogue: bias + relu -> bf16 into LDS O1
#pragma unroll
        for (int nt = 0; nt < 8; nt++) {
            int col = h * 128 + nt * 16 + l16;
            float bcol = bias1[col];
#pragma unroll
            for (int r = 0; r < 4; r++) {
                int row = wave * 16 + quad * 4 + r;
                O1[row][col] = f2bf(fmaxf(acc[nt][r] + bcol, 0.f));
            }
        }
    }
    __syncthreads();   // all O1 writes visible before phase 2 reads

    // ---- phase 2: K=256 from O1 (LDS), per col-half y ----
    for (int y = 0; y < 2; y++) {
        floatx4 acc[8];
#pragma unroll
        for (int i = 0; i < 8; i++) acc[i] = (floatx4){0.f, 0.f, 0.f, 0.f};
        const ushort* Bp0 = B2t + (size_t)(y * 128 + ar) * 256 + ac;
        const ushort* Bp1 = Bp0 + (size_t)64 * 256;

        for (int k0 = 0; k0 < 256; k0 += 32) {
            uint4 b0  = *reinterpret_cast<const uint4*>(Bp0 + k0);
            uint4 b1v = *reinterpret_cast<const uint4*>(Bp1 + k0);
            __syncthreads();             // prior MFMAs (reading Bs) done
            *reinterpret_cast<uint4*>(&Bs[ar][ac])      = b0;
            *reinterpret_cast<uint4*>(&Bs[64 + ar][ac]) = b1v;
            __syncthreads();
            afr.u = *reinterpret_cast<const uint4*>(&O1[wave * 16 + l16][k0 + quad * 8]);
#pragma unroll
            for (int nt = 0; nt < 8; nt++) {
                bfr.u = *reinterpret_cast<const uint4*>(&Bs[nt * 16 + l16][quad * 8]);
                acc[nt] = __builtin_amdgcn_mfma_f32_16x16x32_bf16(afr.s, bfr.s, acc[nt], 0, 0, 0);
            }
        }
        // epilogue: h2 write + layer-2 attention logits (head = y)
#pragma unroll
        for (int nt = 0; nt < 8; nt++) {
            int col = y * 128 + nt * 16 + l16;
#pragma unroll
            for (int r = 0; r < 4; r++) {
                size_t row = rowBase + wave * 16 + quad * 4 + r;
                C[row * F2 + col] = f2bf(acc[nt][r]);
            }
        }
        float aSv[8], aDv[8];
#pragma unroll
        for (int nt = 0; nt < 8; nt++) {
            int c = y * 128 + nt * 16 + l16;
            aSv[nt] = aS[c];
            aDv[nt] = aD[c];
        }
#pragma unroll
        for (int r = 0; r < 4; r++) {
            float ps = 0.f, pd = 0.f;
#pragma unroll
            for (int nt = 0; nt < 8; nt++) {
                ps += acc[nt][r] * aSv[nt];
                pd += acc[nt][r] * aDv[nt];
            }
#pragma unroll
            for (int o = 1; o < 16; o <<= 1) {
                ps += __shfl_xor(ps, o);
                pd += __shfl_xor(pd, o);
            }
            if (l16 == 0) {
                size_t row = rowBase + wave * 16 + quad * 4 + r;
                as_f[2 * row + y] = ps;
                ad_f[2 * row + y] = pd;
            }
        }
    }
}

// ---------------------------------------------------------------------------
// layer-2 gather (R1-proven structure): 512B rows, half-wave edge split,
// uint4 16B/lane, masked 4-wide tail. final_mode=1: fused post_mp + sigmoid.
// ---------------------------------------------------------------------------
__global__ __launch_bounds__(256) void gather_kernel(const uint2* __restrict__ hb2,
                                                     const int* __restrict__ row_start,
                                                     const int* __restrict__ csr_src,
                                                     const float2* __restrict__ as_,
                                                     const float2* __restrict__ ad_,
                                                     const float4* __restrict__ bias4,
                                                     uint2* __restrict__ outb2,
                                                     const float4* __restrict__ WfA,
                                                     const float* __restrict__ bfv,
                                                     float2* __restrict__ outp,
                                                     int final_mode) {
    int wave = threadIdx.x >> 6, lane = threadIdx.x & 63;
    int n = blockIdx.x * 4 + wave;
    if (n >= NNODES) return;
    int beg = __builtin_amdgcn_readfirstlane(row_start[n]);
    int end = __builtin_amdgcn_readfirstlane(row_start[n + 1]);
    int fl   = lane & 31;          // feature lane: covers cols fl*8 .. fl*8+7
    int half = lane >> 5;          // which edge of each pair this lane handles
    bool head1 = (fl >= 16);       // cols 128-255 are head 1
    float2 ad = ad_[n];
    float adsel = head1 ? ad.y : ad.x;

    float a0 = 0.f, a1 = 0.f, a2 = 0.f, a3 = 0.f;
    float a4 = 0.f, a5 = 0.f, a6 = 0.f, a7 = 0.f;
    float aden = 0.f;
    const char* hbase = (const char*)hb2;
    uint laneoff = (uint)fl * 16u;

    int j = beg;
    for (; j + 3 < end; j += 4) {
        int e0 = j + 2 * half, e1 = e0 + 1;
        int s0 = csr_src[e0], s1 = csr_src[e1];
        float2 q0 = as_[s0], q1 = as_[s1];
        uint4 h0 = *(const uint4*)(hbase + (size_t)(((uint)s0 << 9) + laneoff));
        uint4 h1 = *(const uint4*)(hbase + (size_t)(((uint)s1 << 9) + laneoff));
        float l0 = (head1 ? q0.y : q0.x) + adsel; l0 = fmaxf(l0, NEG_SLOPE * l0);
        float l1 = (head1 ? q1.y : q1.x) + adsel; l1 = fmaxf(l1, NEG_SLOPE * l1);
        float w0 = __expf(l0), w1 = __expf(l1);
        aden += w0 + w1;
        a0 += w0 * bf2f(h0.x & 0xffffu) + w1 * bf2f(h1.x & 0xffffu);
        a1 += w0 * bf2f(h0.x >> 16)     + w1 * bf2f(h1.x >> 16);
        a2 += w0 * bf2f(h0.y & 0xffffu) + w1 * bf2f(h1.y & 0xffffu);
        a3 += w0 * bf2f(h0.y >> 16)     + w1 * bf2f(h1.y >> 16);
        a4 += w0 * bf2f(h0.z & 0xffffu) + w1 * bf2f(h1.z & 0xffffu);
        a5 += w0 * bf2f(h0.z >> 16)     + w1 * bf2f(h1.z >> 16);
        a6 += w0 * bf2f(h0.w & 0xffffu) + w1 * bf2f(h1.w & 0xffffu);
        a7 += w0 * bf2f(h0.w >> 16)     + w1 * bf2f(h1.w >> 16);
    }
    if (j < end) {                 // masked 4-wide tail (clamped idx = hot line)
        int e0 = j + 2 * half, e1 = e0 + 1;
        int c0 = e0 < end ? e0 : end - 1;
        int c1 = e1 < end ? e1 : end - 1;
        int s0 = csr_src[c0], s1 = csr_src[c1];
        float2 q0 = as_[s0], q1 = as_[s1];
        uint4 h0 = *(const uint4*)(hbase + (size_t)(((uint)s0 << 9) + laneoff));
        uint4 h1 = *(const uint4*)(hbase + (size_t)(((uint)s1 << 9) + laneoff));
        float l0 = (head1 ? q0.y : q0.x) + adsel; l0 = fmaxf(l0, NEG_SLOPE * l0);
        float l1 = (head1 ? q1.y : q1.x) + adsel; l1 = fmaxf(l1, NEG_SLOPE * l1);
        float w0 = (e0 < end) ? __expf(l0) : 0.f;
        float w1 = (e1 < end) ? __expf(l1) : 0.f;
        aden += w0 + w1;
        a0 += w0 * bf2f(h0.x & 0xffffu) + w1 * bf2f(h1.x & 0xffffu);
        a1 += w0 * bf2f(h0.x >> 16)     + w1 * bf2f(h1.x >> 16);
        a2 += w0 * bf2f(h0.y & 0xffffu) + w1 * bf2f(h1.y & 0xffffu);
        a3 += w0 * bf2f(h0.y >> 16)     + w1 * bf2f(h1.y >> 16);
        a4 += w0 * bf2f(h0.z & 0xffffu) + w1 * bf2f(h1.z & 0xffffu);
        a5 += w0 * bf2f(h0.z >> 16)     + w1 * bf2f(h1.z >> 16);
        a6 += w0 * bf2f(h0.w & 0xffffu) + w1 * bf2f(h1.w & 0xffffu);
        a7 += w0 * bf2f(h0.w >> 16)     + w1 * bf2f(h1.w >> 16);
    }

    // combine the two half-wave partials (features AND denominator)
    aden += __shfl_xor(aden, 32);
    a0 += __shfl_xor(a0, 32);  a1 += __shfl_xor(a1, 32);
    a2 += __shfl_xor(a2, 32);  a3 += __shfl_xor(a3, 32);
    a4 += __shfl_xor(a4, 32);  a5 += __shfl_xor(a5, 32);
    a6 += __shfl_xor(a6, 32);  a7 += __shfl_xor(a7, 32);

    float inv = 1.f / (aden + 1e-16f);
    float4 ba = bias4[2 * fl];
    float4 bb = bias4[2 * fl + 1];
    float o0 = fmaxf(a0 * inv + ba.x, 0.f);
    float o1 = fmaxf(a1 * inv + ba.y, 0.f);
    float o2 = fmaxf(a2 * inv + ba.z, 0.f);
    float o3 = fmaxf(a3 * inv + ba.w, 0.f);
    float o4 = fmaxf(a4 * inv + bb.x, 0.f);
    float o5 = fmaxf(a5 * inv + bb.y, 0.f);
    float o6 = fmaxf(a6 * inv + bb.z, 0.f);
    float o7 = fmaxf(a7 * inv + bb.w, 0.f);
    if (!final_mode) {
        if (half == 0) {
            uint4 pk;
            pk.x = (uint)f2bf(o0) | ((uint)f2bf(o1) << 16);
            pk.y = (uint)f2bf(o2) | ((uint)f2bf(o3) << 16);
            pk.z = (uint)f2bf(o4) | ((uint)f2bf(o5) << 16);
            pk.w = (uint)f2bf(o6) | ((uint)f2bf(o7) << 16);
            *(uint4*)((char*)outb2 + (size_t)n * 512 + (size_t)fl * 16) = pk;
        }
    } else {
        float4 wa = WfA[4 * fl + 0];
        float4 wb = WfA[4 * fl + 1];
        float4 wc = WfA[4 * fl + 2];
        float4 wd = WfA[4 * fl + 3];
        float p0 = o0 * wa.x + o1 * wa.z + o2 * wb.x + o3 * wb.z
                 + o4 * wc.x + o5 * wc.z + o6 * wd.x + o7 * wd.z;
        float p1 = o0 * wa.y + o1 * wa.w + o2 * wb.y + o3 * wb.w
                 + o4 * wc.y + o5 * wc.w + o6 * wd.y + o7 * wd.w;
#pragma unroll
        for (int o = 16; o; o >>= 1) {
            p0 += __shfl_xor(p0, o);
            p1 += __shfl_xor(p1, o);
        }
        if (lane == 0) {
            float2 r;
            r.x = 1.f / (1.f + __expf(-(p0 + bfv[0])));
            r.y = 1.f / (1.f + __expf(-(p1 + bfv[1])));
            outp[n] = r;
        }
    }
}

// ---------------------------------------------------------------------------
extern "C" void kernel_launch(void* const* d_in, const int* in_sizes, int n_in,
                              void* d_out, int out_size, void* d_ws, size_t ws_size,
                              hipStream_t stream) {
    const float* x      = (const float*)d_in[0];
    const int*   ei     = (const int*)d_in[1];
    const float* W1     = (const float*)d_in[2];
    const float* a_src1 = (const float*)d_in[3];
    const float* a_dst1 = (const float*)d_in[4];
    const float* b1     = (const float*)d_in[5];
    const float* W2     = (const float*)d_in[6];
    const float* a_src2 = (const float*)d_in[7];
    const float* a_dst2 = (const float*)d_in[8];
    const float* b2     = (const float*)d_in[9];
    const float* Wp1    = (const float*)d_in[10];
    const float* bp1    = (const float*)d_in[11];
    const float* Wp2    = (const float*)d_in[12];
    const float* bp2    = (const float*)d_in[13];
    float* outp = (float*)d_out;

    // workspace carve-up (all regions 16B aligned)
    char* w = (char*)d_ws;
    ushort* hbf  = (ushort*)w; w += (size_t)NPAD * 256 * sizeof(ushort);  // 51.2MB (xb first, then h2)
    ushort* obf  = (ushort*)w; w += (size_t)NPAD * 256 * sizeof(ushort);  // 51.2MB (g1; outb2 scratch)
    ushort* W1t  = (ushort*)w; w += (size_t)256 * 128 * sizeof(ushort);
    ushort* W2t  = (ushort*)w; w += (size_t)256 * 256 * sizeof(ushort);
    float2* Wf   = (float2*)w; w += 256 * sizeof(float2);
    float*  bfv  = (float*)w;  w += 4 * sizeof(float);
    float*  va   = (float*)w;  w += 512 * sizeof(float);
    float2* as1  = (float2*)w; w += (size_t)NPAD * sizeof(float2);
    float2* ad1  = (float2*)w; w += (size_t)NPAD * sizeof(float2);
    float2* as2  = (float2*)w; w += (size_t)NPAD * sizeof(float2);
    float2* ad2  = (float2*)w; w += (size_t)NPAD * sizeof(float2);
    int* deg       = (int*)w; w += (size_t)NNODES * sizeof(int);
    int* row_start = (int*)w; w += (size_t)(NNODES + 16) * sizeof(int);
    int* cursor    = (int*)w; w += (size_t)NNODES * sizeof(int);
    int* csr_src   = (int*)w; w += (size_t)ETOT * sizeof(int);

    const int NODE_WAVES = (NNODES + 3) / 4;        // 25000
    const int MB = NPAD / 64;                       // 1563

    // --- CSR build + weight prep ---
    hipMemsetAsync(deg, 0, (size_t)NNODES * sizeof(int), stream);
    setup1_kernel<<<HIST_BLOCKS + 386, 256, 0, stream>>>(ei, deg, W1, W1t, W2, W2t,
                                                         Wp1, bp1, Wp2, bp2, Wf, bfv,
                                                         a_src1, a_dst1, va);
    scan_one_kernel<<<1, 1024, 0, stream>>>(deg, row_start, cursor);

    // --- scatter + alpha_x (independent, merged into one dispatch) ---
    ushort* xb = hbf;   // 25.6MB bf16 x (first half of hbf; dead before h2 write)
    scatter_alpha_kernel<<<ALPHA_BLOCKS + HIST_BLOCKS, 256, 0, stream>>>(
        ei, cursor, csr_src, x, (const float4*)va, (uint*)xb, as1, ad1);

    // --- layer-1 gather in input space (full-occupancy standalone) ---
    gather1_kernel<<<NODE_WAVES, 256, 0, stream>>>((const uint*)xb, row_start, csr_src,
                                                   as1, ad1, obf);

    // --- fused GEMM: g1 -> (relu GEMM1 in LDS) -> GEMM2 -> h2 + logits2 ---
    mfma_gemm_fused<<<MB, 256, 0, stream>>>(obf, W1t, b1, W2t, hbf,
                                            (float*)as2, (float*)ad2, a_src2, a_dst2);

    // --- layer 2 gather fused with post_mp + sigmoid ---
    gather_kernel<<<NODE_WAVES, 256, 0, stream>>>((const uint2*)hbf, row_start, csr_src,
                                                  as2, ad2, (const float4*)b2, (uint2*)obf,
                                                  (const float4*)Wf, bfv, (float2*)outp, 1);
}

// Round 7
// 413.301 us; speedup vs baseline: 1.5639x; 1.5639x over previous
//
#include <hip/hip_runtime.h>
#include <hip/hip_bf16.h>
#include <math.h>

// Problem constants (match reference)
#define NNODES 100000
#define NPAD   100032        // padded to multiple of 64 for guard-free GEMM
#define IN_DIM 128
#define HID 128
#define HEADS 2
#define F2 256               // HEADS*HID
#define NEDGES 800000
#define ETOT 900000          // NEDGES + NNODES self-loops
#define NEG_SLOPE 0.2f
#define HIST_BLOCKS 3516     // (ETOT+255)/256
#define ALPHA_BLOCKS 25000   // NNODES/4 waves

typedef unsigned int uint;
typedef unsigned short ushort;
typedef __attribute__((ext_vector_type(8))) short short8;
typedef __attribute__((ext_vector_type(4))) float floatx4;

__device__ __forceinline__ ushort f2bf(float f) {
    uint u = __builtin_bit_cast(uint, f);
    u += 0x7fffu + ((u >> 16) & 1u);       // round-to-nearest-even
    return (ushort)(u >> 16);
}
__device__ __forceinline__ float bf2f(uint u16) {
    return __builtin_bit_cast(float, u16 << 16);
}

// ---------------------------------------------------------------------------
// setup1: histogram (blocks [0,HIST_BLOCKS)) merged with weight prep.
// prep: W1^T, W2^T (bf16) + fused post_mp weights + layer-1 projection
// vectors va[k] = (W1h0@a_src1h0, W1h1@a_src1h1, W1h0@a_dst1h0, W1h1@a_dst1h1)
// ---------------------------------------------------------------------------
__global__ __launch_bounds__(256) void setup1_kernel(const int* __restrict__ ei,
                                                     int* __restrict__ deg,
                                                     const float* __restrict__ W1,
                                                     ushort* __restrict__ W1t,
                                                     const float* __restrict__ W2,
                                                     ushort* __restrict__ W2t,
                                                     const float* __restrict__ Wp1,
                                                     const float* __restrict__ bp1,
                                                     const float* __restrict__ Wp2,
                                                     const float* __restrict__ bp2,
                                                     float2* __restrict__ Wf,
                                                     float* __restrict__ bfv,
                                                     const float* __restrict__ a_src1,
                                                     const float* __restrict__ a_dst1,
                                                     float* __restrict__ va) {
    int b = blockIdx.x, t = threadIdx.x;
    if (b < HIST_BLOCKS) {               // histogram
        int i = b * 256 + t;
        if (i >= ETOT) return;
        int dst = (i < NEDGES) ? ei[NEDGES + i] : (i - NEDGES);
        atomicAdd(&deg[dst], 1);
        return;
    }
    int b2 = b - HIST_BLOCKS;
    if (b2 < 128) {                      // W1t[n][k] = W1[k][n], K=128, N=256
        int i = b2 * 256 + t;
        int n = i >> 7, k = i & 127;
        W1t[n * 128 + k] = f2bf(W1[k * 256 + n]);
    } else if (b2 < 384) {               // W2t[n][k] = W2[k][n], K=256, N=256
        int i = (b2 - 128) * 256 + t;
        int n = i >> 8, k = i & 255;
        W2t[n * 256 + k] = f2bf(W2[k * 256 + n]);
    } else if (b2 == 384) {              // Wf[k] = Wp1[k][:] @ Wp2 ; bfv
        float s0 = 0.f, s1 = 0.f;
        for (int m = 0; m < 128; m++) {
            float w = Wp1[t * 128 + m];
            s0 += w * Wp2[2 * m];
            s1 += w * Wp2[2 * m + 1];
        }
        Wf[t] = make_float2(s0, s1);
        if (t < 2) {
            float bb = bp2[t];
            for (int m = 0; m < 128; m++) bb += bp1[m] * Wp2[2 * m + t];
            bfv[t] = bb;
        }
    } else {                             // va projection vectors (f32, exact)
        int k = t & 127, sel = t >> 7;   // sel 0 = src, 1 = dst
        const float* av = sel ? a_dst1 : a_src1;   // [2][128]
        float s0 = 0.f, s1 = 0.f;
        for (int j = 0; j < 128; j++) {
            s0 += W1[k * 256 + j]       * av[j];
            s1 += W1[k * 256 + 128 + j] * av[128 + j];
        }
        va[k * 4 + sel * 2 + 0] = s0;
        va[k * 4 + sel * 2 + 1] = s1;
    }
}

// ---------------------------------------------------------------------------
// CSR scan (R4-proven, parallel 391-block): per-block scan -> fixup.
// (R6 lesson: single-workgroup scan = 233us; parallel 2-dispatch = ~10us.)
// ---------------------------------------------------------------------------
__global__ __launch_bounds__(256) void scan1_kernel(const int* __restrict__ deg,
                                                    int* __restrict__ row_start,
                                                    int* __restrict__ bsum) {
    __shared__ int s[256];
    int t = threadIdx.x;
    int i = blockIdx.x * 256 + t;
    int v = (i < NNODES) ? deg[i] : 0;
    s[t] = v;
    __syncthreads();
    for (int off = 1; off < 256; off <<= 1) {
        int x = (t >= off) ? s[t - off] : 0;
        __syncthreads();
        s[t] += x;
        __syncthreads();
    }
    if (i < NNODES) row_start[i] = s[t] - v;   // exclusive within block
    if (t == 255) bsum[blockIdx.x] = s[255];
}

__global__ __launch_bounds__(256) void scan_fix_kernel(int* __restrict__ row_start,
                                                       const int* __restrict__ bsum,
                                                       int* __restrict__ cursor) {
    __shared__ int sh[256];
    int t = threadIdx.x, bid = blockIdx.x;
    int v = 0;
    for (int k = t; k < bid; k += 256) v += bsum[k];
    sh[t] = v;
    __syncthreads();
    for (int off = 128; off; off >>= 1) {
        if (t < off) sh[t] += sh[t + off];
        __syncthreads();
    }
    int boff = sh[0];
    int i = bid * 256 + t;
    if (i == 0) row_start[NNODES] = ETOT;
    if (i < NNODES) {
        int r = row_start[i] + boff;
        row_start[i] = r;
        cursor[i] = r;
    }
}

// ---------------------------------------------------------------------------
// scatter_alpha: blocks [0,ALPHA_BLOCKS) = alpha_x (per node: xb bf16 pack +
// layer-1 logits as1/ad1 = x.va); blocks [ALPHA_BLOCKS,..) = CSR scatter.
// Independent latency-bound work overlapped in one dispatch.
// ---------------------------------------------------------------------------
__global__ __launch_bounds__(256) void scatter_alpha_kernel(const int* __restrict__ ei,
                                                            int* __restrict__ cursor,
                                                            int* __restrict__ csr_src,
                                                            const float* __restrict__ x,
                                                            const float4* __restrict__ va4,
                                                            uint* __restrict__ xb,
                                                            float2* __restrict__ as_,
                                                            float2* __restrict__ ad_) {
    int b = blockIdx.x;
    if (b < ALPHA_BLOCKS) {              // alpha_x path
        int wave = threadIdx.x >> 6, lane = threadIdx.x & 63;
        int n = b * 4 + wave;
        if (n >= NNODES) return;
        float2 xv = *reinterpret_cast<const float2*>(x + (size_t)n * 128 + lane * 2);
        xb[(size_t)n * 64 + lane] = (uint)f2bf(xv.x) | ((uint)f2bf(xv.y) << 16);
        float4 v0 = va4[2 * lane];       // feat k = 2*lane: (src0,src1,dst0,dst1)
        float4 v1 = va4[2 * lane + 1];   // feat k = 2*lane+1
        float ss0 = xv.x * v0.x + xv.y * v1.x;
        float ss1 = xv.x * v0.y + xv.y * v1.y;
        float sd0 = xv.x * v0.z + xv.y * v1.z;
        float sd1 = xv.x * v0.w + xv.y * v1.w;
#pragma unroll
        for (int o = 32; o; o >>= 1) {
            ss0 += __shfl_xor(ss0, o);
            ss1 += __shfl_xor(ss1, o);
            sd0 += __shfl_xor(sd0, o);
            sd1 += __shfl_xor(sd1, o);
        }
        if (lane == 0) {
            as_[n] = make_float2(ss0, ss1);
            ad_[n] = make_float2(sd0, sd1);
        }
        return;
    }
    int i = (b - ALPHA_BLOCKS) * 256 + threadIdx.x;   // scatter path
    if (i >= ETOT) return;
    int src, dst;
    if (i < NEDGES) { src = ei[i]; dst = ei[NEDGES + i]; }
    else            { src = i - NEDGES; dst = src; }
    int pos = atomicAdd(&cursor[dst], 1);
    csr_src[pos] = src;
}

// ---------------------------------------------------------------------------
// layer-1 gather in INPUT space: 256B bf16 rows (xb). 4-way quad split.
// Output g1 row = [head0 128 bf16 | head1 128 bf16] (512B). No bias/relu
// (moved to fused GEMM phase-1 epilogue). Full-occupancy (no LDS, 24 VGPR) —
// R5 proved merging this into the GEMM kernel kills it via occupancy.
// ---------------------------------------------------------------------------
__global__ __launch_bounds__(256) void gather1_kernel(const uint* __restrict__ xb,
                                                      const int* __restrict__ row_start,
                                                      const int* __restrict__ csr_src,
                                                      const float2* __restrict__ as_,
                                                      const float2* __restrict__ ad_,
                                                      ushort* __restrict__ g1) {
    int wave = threadIdx.x >> 6, lane = threadIdx.x & 63;
    int n = blockIdx.x * 4 + wave;
    if (n >= NNODES) return;
    int beg = __builtin_amdgcn_readfirstlane(row_start[n]);
    int end = __builtin_amdgcn_readfirstlane(row_start[n + 1]);
    int fl = lane & 15;            // feature lane: bytes fl*16 .. fl*16+15
    int q  = lane >> 4;            // quad: edge base+q
    float2 ad = ad_[n];
    float ad0 = ad.x, ad1 = ad.y;

    float a00 = 0.f, a01 = 0.f, a02 = 0.f, a03 = 0.f;
    float a04 = 0.f, a05 = 0.f, a06 = 0.f, a07 = 0.f;   // head0
    float a10 = 0.f, a11 = 0.f, a12 = 0.f, a13 = 0.f;
    float a14 = 0.f, a15 = 0.f, a16 = 0.f, a17 = 0.f;   // head1
    float aden0 = 0.f, aden1 = 0.f;
    const char* hbase = (const char*)xb;
    uint laneoff = (uint)fl * 16u;
    int last = end - 1;

    for (int j = beg; j < end; j += 4) {
        int e = j + q;
        int c = e < end ? e : last;
        int s = csr_src[c];
        uint4 h = *(const uint4*)(hbase + (size_t)(((uint)s << 8) + laneoff));
        float2 qv = as_[s];
        float l0 = qv.x + ad0; l0 = fmaxf(l0, NEG_SLOPE * l0);
        float l1 = qv.y + ad1; l1 = fmaxf(l1, NEG_SLOPE * l1);
        float w0 = (e < end) ? __expf(l0) : 0.f;
        float w1 = (e < end) ? __expf(l1) : 0.f;
        aden0 += w0; aden1 += w1;
        float f0 = bf2f(h.x & 0xffffu), f1 = bf2f(h.x >> 16);
        float f2 = bf2f(h.y & 0xffffu), f3 = bf2f(h.y >> 16);
        float f4 = bf2f(h.z & 0xffffu), f5 = bf2f(h.z >> 16);
        float f6 = bf2f(h.w & 0xffffu), f7 = bf2f(h.w >> 16);
        a00 += w0 * f0; a01 += w0 * f1; a02 += w0 * f2; a03 += w0 * f3;
        a04 += w0 * f4; a05 += w0 * f5; a06 += w0 * f6; a07 += w0 * f7;
        a10 += w1 * f0; a11 += w1 * f1; a12 += w1 * f2; a13 += w1 * f3;
        a14 += w1 * f4; a15 += w1 * f5; a16 += w1 * f6; a17 += w1 * f7;
    }

    // cross-quad reduction (xor 16 then 32 -> every lane holds totals)
#pragma unroll
    for (int o = 16; o <= 32; o <<= 1) {
        aden0 += __shfl_xor(aden0, o); aden1 += __shfl_xor(aden1, o);
        a00 += __shfl_xor(a00, o); a01 += __shfl_xor(a01, o);
        a02 += __shfl_xor(a02, o); a03 += __shfl_xor(a03, o);
        a04 += __shfl_xor(a04, o); a05 += __shfl_xor(a05, o);
        a06 += __shfl_xor(a06, o); a07 += __shfl_xor(a07, o);
        a10 += __shfl_xor(a10, o); a11 += __shfl_xor(a11, o);
        a12 += __shfl_xor(a12, o); a13 += __shfl_xor(a13, o);
        a14 += __shfl_xor(a14, o); a15 += __shfl_xor(a15, o);
        a16 += __shfl_xor(a16, o); a17 += __shfl_xor(a17, o);
    }
    float inv0 = 1.f / (aden0 + 1e-16f);
    float inv1 = 1.f / (aden1 + 1e-16f);
    if (q == 0) {                  // head0 bytes [0,256)
        uint4 pk;
        pk.x = (uint)f2bf(a00 * inv0) | ((uint)f2bf(a01 * inv0) << 16);
        pk.y = (uint)f2bf(a02 * inv0) | ((uint)f2bf(a03 * inv0) << 16);
        pk.z = (uint)f2bf(a04 * inv0) | ((uint)f2bf(a05 * inv0) << 16);
        pk.w = (uint)f2bf(a06 * inv0) | ((uint)f2bf(a07 * inv0) << 16);
        *(uint4*)((char*)g1 + (size_t)n * 512 + fl * 16) = pk;
    } else if (q == 1) {           // head1 bytes [256,512)
        uint4 pk;
        pk.x = (uint)f2bf(a10 * inv1) | ((uint)f2bf(a11 * inv1) << 16);
        pk.y = (uint)f2bf(a12 * inv1) | ((uint)f2bf(a13 * inv1) << 16);
        pk.z = (uint)f2bf(a14 * inv1) | ((uint)f2bf(a15 * inv1) << 16);
        pk.w = (uint)f2bf(a16 * inv1) | ((uint)f2bf(a17 * inv1) << 16);
        *(uint4*)((char*)g1 + (size_t)n * 512 + 256 + fl * 16) = pk;
    }
}

// ---------------------------------------------------------------------------
// FUSED double GEMM per 64-row block (R4-proven):
//   phase 1 (per head h): out1[:,h*128:] = relu(g1[:,h*128:] @ W1_h + b1_h)
//            -> stored in LDS O1[64][264] as bf16 (never touches HBM)
//   phase 2 (per col-half y): h2[:, y*128:] = out1 @ W2[:, y*128:]
//            A-fragments read DIRECTLY from O1 (zero A staging),
//            epilogue writes h2 + layer-2 attention logits as2/ad2.
// ---------------------------------------------------------------------------
__global__ __launch_bounds__(256) void mfma_gemm_fused(const ushort* __restrict__ A,
                                                       const ushort* __restrict__ B1t,
                                                       const float* __restrict__ bias1,
                                                       const ushort* __restrict__ B2t,
                                                       ushort* __restrict__ C,
                                                       float* __restrict__ as_f,
                                                       float* __restrict__ ad_f,
                                                       const float* __restrict__ aS,
                                                       const float* __restrict__ aD) {
    __shared__ ushort As[64][40];
    __shared__ ushort Bs[128][40];
    __shared__ ushort O1[64][264];   // row stride 528B: 16B-aligned
    int t = threadIdx.x;
    int wave = t >> 6, lane = t & 63;
    int quad = lane >> 4, l16 = lane & 15;
    size_t rowBase = (size_t)blockIdx.x * 64;
    int ar = t >> 2, ac = (t & 3) * 8;
    union { uint4 u; short8 s; } afr, bfr;

    // ---- phase 1: two heads, K=128 each ----
    for (int h = 0; h < 2; h++) {
        floatx4 acc[8];
#pragma unroll
        for (int i = 0; i < 8; i++) acc[i] = (floatx4){0.f, 0.f, 0.f, 0.f};
        const ushort* Ap  = A + (rowBase + ar) * 256 + h * 128 + ac;  // lda=256
        const ushort* Bp0 = B1t + (size_t)(h * 128 + ar) * 128 + ac;
        const ushort* Bp1 = Bp0 + (size_t)64 * 128;

        for (int k0 = 0; k0 < 128; k0 += 32) {
            uint4 av  = *reinterpret_cast<const uint4*>(Ap + k0);
            uint4 b0  = *reinterpret_cast<const uint4*>(Bp0 + k0);
            uint4 b1v = *reinterpret_cast<const uint4*>(Bp1 + k0);
            __syncthreads();             // prior MFMAs / O1 stores done
            *reinterpret_cast<uint4*>(&As[ar][ac])      = av;
            *reinterpret_cast<uint4*>(&Bs[ar][ac])      = b0;
            *reinterpret_cast<uint4*>(&Bs[64 + ar][ac]) = b1v;
            __syncthreads();
            afr.u = *reinterpret_cast<const uint4*>(&As[wave * 16 + l16][quad * 8]);
#pragma unroll
            for (int nt = 0; nt < 8; nt++) {
                bfr.u = *reinterpret_cast<const uint4*>(&Bs[nt * 16 + l16][quad * 8]);
                acc[nt] = __builtin_amdgcn_mfma_f32_16x16x32_bf16(afr.s, bfr.s, acc[nt], 0, 0, 0);
            }
        }
        // epilogue: bias + relu -> bf16 into LDS O1
#pragma unroll
        for (int nt = 0; nt < 8; nt++) {
            int col = h * 128 + nt * 16 + l16;
            float bcol = bias1[col];
#pragma unroll
            for (int r = 0; r < 4; r++) {
                int row = wave * 16 + quad * 4 + r;
                O1[row][col] = f2bf(fmaxf(acc[nt][r] + bcol, 0.f));
            }
        }
    }
    __syncthreads();   // all O1 writes visible before phase 2 reads

    // ---- phase 2: K=256 from O1 (LDS), per col-half y ----
    for (int y = 0; y < 2; y++) {
        floatx4 acc[8];
#pragma unroll
        for (int i = 0; i < 8; i++) acc[i] = (floatx4){0.f, 0.f, 0.f, 0.f};
        const ushort* Bp0 = B2t + (size_t)(y * 128 + ar) * 256 + ac;
        const ushort* Bp1 = Bp0 + (size_t)64 * 256;

        for (int k0 = 0; k0 < 256; k0 += 32) {
            uint4 b0  = *reinterpret_cast<const uint4*>(Bp0 + k0);
            uint4 b1v = *reinterpret_cast<const uint4*>(Bp1 + k0);
            __syncthreads();             // prior MFMAs (reading Bs) done
            *reinterpret_cast<uint4*>(&Bs[ar][ac])      = b0;
            *reinterpret_cast<uint4*>(&Bs[64 + ar][ac]) = b1v;
            __syncthreads();
            afr.u = *reinterpret_cast<const uint4*>(&O1[wave * 16 + l16][k0 + quad * 8]);
#pragma unroll
            for (int nt = 0; nt < 8; nt++) {
                bfr.u = *reinterpret_cast<const uint4*>(&Bs[nt * 16 + l16][quad * 8]);
                acc[nt] = __builtin_amdgcn_mfma_f32_16x16x32_bf16(afr.s, bfr.s, acc[nt], 0, 0, 0);
            }
        }
        // epilogue: h2 write + layer-2 attention logits (head = y)
#pragma unroll
        for (int nt = 0; nt < 8; nt++) {
            int col = y * 128 + nt * 16 + l16;
#pragma unroll
            for (int r = 0; r < 4; r++) {
                size_t row = rowBase + wave * 16 + quad * 4 + r;
                C[row * F2 + col] = f2bf(acc[nt][r]);
            }
        }
        float aSv[8], aDv[8];
#pragma unroll
        for (int nt = 0; nt < 8; nt++) {
            int c = y * 128 + nt * 16 + l16;
            aSv[nt] = aS[c];
            aDv[nt] = aD[c];
        }
#pragma unroll
        for (int r = 0; r < 4; r++) {
            float ps = 0.f, pd = 0.f;
#pragma unroll
            for (int nt = 0; nt < 8; nt++) {
                ps += acc[nt][r] * aSv[nt];
                pd += acc[nt][r] * aDv[nt];
            }
#pragma unroll
            for (int o = 1; o < 16; o <<= 1) {
                ps += __shfl_xor(ps, o);
                pd += __shfl_xor(pd, o);
            }
            if (l16 == 0) {
                size_t row = rowBase + wave * 16 + quad * 4 + r;
                as_f[2 * row + y] = ps;
                ad_f[2 * row + y] = pd;
            }
        }
    }
}

// ---------------------------------------------------------------------------
// layer-2 gather (R1-proven structure): 512B rows, half-wave edge split,
// uint4 16B/lane, masked 4-wide tail. final_mode=1: fused post_mp + sigmoid.
// ---------------------------------------------------------------------------
__global__ __launch_bounds__(256) void gather_kernel(const uint2* __restrict__ hb2,
                                                     const int* __restrict__ row_start,
                                                     const int* __restrict__ csr_src,
                                                     const float2* __restrict__ as_,
                                                     const float2* __restrict__ ad_,
                                                     const float4* __restrict__ bias4,
                                                     uint2* __restrict__ outb2,
                                                     const float4* __restrict__ WfA,
                                                     const float* __restrict__ bfv,
                                                     float2* __restrict__ outp,
                                                     int final_mode) {
    int wave = threadIdx.x >> 6, lane = threadIdx.x & 63;
    int n = blockIdx.x * 4 + wave;
    if (n >= NNODES) return;
    int beg = __builtin_amdgcn_readfirstlane(row_start[n]);
    int end = __builtin_amdgcn_readfirstlane(row_start[n + 1]);
    int fl   = lane & 31;          // feature lane: covers cols fl*8 .. fl*8+7
    int half = lane >> 5;          // which edge of each pair this lane handles
    bool head1 = (fl >= 16);       // cols 128-255 are head 1
    float2 ad = ad_[n];
    float adsel = head1 ? ad.y : ad.x;

    float a0 = 0.f, a1 = 0.f, a2 = 0.f, a3 = 0.f;
    float a4 = 0.f, a5 = 0.f, a6 = 0.f, a7 = 0.f;
    float aden = 0.f;
    const char* hbase = (const char*)hb2;
    uint laneoff = (uint)fl * 16u;

    int j = beg;
    for (; j + 3 < end; j += 4) {
        int e0 = j + 2 * half, e1 = e0 + 1;
        int s0 = csr_src[e0], s1 = csr_src[e1];
        float2 q0 = as_[s0], q1 = as_[s1];
        uint4 h0 = *(const uint4*)(hbase + (size_t)(((uint)s0 << 9) + laneoff));
        uint4 h1 = *(const uint4*)(hbase + (size_t)(((uint)s1 << 9) + laneoff));
        float l0 = (head1 ? q0.y : q0.x) + adsel; l0 = fmaxf(l0, NEG_SLOPE * l0);
        float l1 = (head1 ? q1.y : q1.x) + adsel; l1 = fmaxf(l1, NEG_SLOPE * l1);
        float w0 = __expf(l0), w1 = __expf(l1);
        aden += w0 + w1;
        a0 += w0 * bf2f(h0.x & 0xffffu) + w1 * bf2f(h1.x & 0xffffu);
        a1 += w0 * bf2f(h0.x >> 16)     + w1 * bf2f(h1.x >> 16);
        a2 += w0 * bf2f(h0.y & 0xffffu) + w1 * bf2f(h1.y & 0xffffu);
        a3 += w0 * bf2f(h0.y >> 16)     + w1 * bf2f(h1.y >> 16);
        a4 += w0 * bf2f(h0.z & 0xffffu) + w1 * bf2f(h1.z & 0xffffu);
        a5 += w0 * bf2f(h0.z >> 16)     + w1 * bf2f(h1.z >> 16);
        a6 += w0 * bf2f(h0.w & 0xffffu) + w1 * bf2f(h1.w & 0xffffu);
        a7 += w0 * bf2f(h0.w >> 16)     + w1 * bf2f(h1.w >> 16);
    }
    if (j < end) {                 // masked 4-wide tail (clamped idx = hot line)
        int e0 = j + 2 * half, e1 = e0 + 1;
        int c0 = e0 < end ? e0 : end - 1;
        int c1 = e1 < end ? e1 : end - 1;
        int s0 = csr_src[c0], s1 = csr_src[c1];
        float2 q0 = as_[s0], q1 = as_[s1];
        uint4 h0 = *(const uint4*)(hbase + (size_t)(((uint)s0 << 9) + laneoff));
        uint4 h1 = *(const uint4*)(hbase + (size_t)(((uint)s1 << 9) + laneoff));
        float l0 = (head1 ? q0.y : q0.x) + adsel; l0 = fmaxf(l0, NEG_SLOPE * l0);
        float l1 = (head1 ? q1.y : q1.x) + adsel; l1 = fmaxf(l1, NEG_SLOPE * l1);
        float w0 = (e0 < end) ? __expf(l0) : 0.f;
        float w1 = (e1 < end) ? __expf(l1) : 0.f;
        aden += w0 + w1;
        a0 += w0 * bf2f(h0.x & 0xffffu) + w1 * bf2f(h1.x & 0xffffu);
        a1 += w0 * bf2f(h0.x >> 16)     + w1 * bf2f(h1.x >> 16);
        a2 += w0 * bf2f(h0.y & 0xffffu) + w1 * bf2f(h1.y & 0xffffu);
        a3 += w0 * bf2f(h0.y >> 16)     + w1 * bf2f(h1.y >> 16);
        a4 += w0 * bf2f(h0.z & 0xffffu) + w1 * bf2f(h1.z & 0xffffu);
        a5 += w0 * bf2f(h0.z >> 16)     + w1 * bf2f(h1.z >> 16);
        a6 += w0 * bf2f(h0.w & 0xffffu) + w1 * bf2f(h1.w & 0xffffu);
        a7 += w0 * bf2f(h0.w >> 16)     + w1 * bf2f(h1.w >> 16);
    }

    // combine the two half-wave partials (features AND denominator)
    aden += __shfl_xor(aden, 32);
    a0 += __shfl_xor(a0, 32);  a1 += __shfl_xor(a1, 32);
    a2 += __shfl_xor(a2, 32);  a3 += __shfl_xor(a3, 32);
    a4 += __shfl_xor(a4, 32);  a5 += __shfl_xor(a5, 32);
    a6 += __shfl_xor(a6, 32);  a7 += __shfl_xor(a7, 32);

    float inv = 1.f / (aden + 1e-16f);
    float4 ba = bias4[2 * fl];
    float4 bb = bias4[2 * fl + 1];
    float o0 = fmaxf(a0 * inv + ba.x, 0.f);
    float o1 = fmaxf(a1 * inv + ba.y, 0.f);
    float o2 = fmaxf(a2 * inv + ba.z, 0.f);
    float o3 = fmaxf(a3 * inv + ba.w, 0.f);
    float o4 = fmaxf(a4 * inv + bb.x, 0.f);
    float o5 = fmaxf(a5 * inv + bb.y, 0.f);
    float o6 = fmaxf(a6 * inv + bb.z, 0.f);
    float o7 = fmaxf(a7 * inv + bb.w, 0.f);
    if (!final_mode) {
        if (half == 0) {
            uint4 pk;
            pk.x = (uint)f2bf(o0) | ((uint)f2bf(o1) << 16);
            pk.y = (uint)f2bf(o2) | ((uint)f2bf(o3) << 16);
            pk.z = (uint)f2bf(o4) | ((uint)f2bf(o5) << 16);
            pk.w = (uint)f2bf(o6) | ((uint)f2bf(o7) << 16);
            *(uint4*)((char*)outb2 + (size_t)n * 512 + (size_t)fl * 16) = pk;
        }
    } else {
        float4 wa = WfA[4 * fl + 0];
        float4 wb = WfA[4 * fl + 1];
        float4 wc = WfA[4 * fl + 2];
        float4 wd = WfA[4 * fl + 3];
        float p0 = o0 * wa.x + o1 * wa.z + o2 * wb.x + o3 * wb.z
                 + o4 * wc.x + o5 * wc.z + o6 * wd.x + o7 * wd.z;
        float p1 = o0 * wa.y + o1 * wa.w + o2 * wb.y + o3 * wb.w
                 + o4 * wc.y + o5 * wc.w + o6 * wd.y + o7 * wd.w;
#pragma unroll
        for (int o = 16; o; o >>= 1) {
            p0 += __shfl_xor(p0, o);
            p1 += __shfl_xor(p1, o);
        }
        if (lane == 0) {
            float2 r;
            r.x = 1.f / (1.f + __expf(-(p0 + bfv[0])));
            r.y = 1.f / (1.f + __expf(-(p1 + bfv[1])));
            outp[n] = r;
        }
    }
}

// ---------------------------------------------------------------------------
extern "C" void kernel_launch(void* const* d_in, const int* in_sizes, int n_in,
                              void* d_out, int out_size, void* d_ws, size_t ws_size,
                              hipStream_t stream) {
    const float* x      = (const float*)d_in[0];
    const int*   ei     = (const int*)d_in[1];
    const float* W1     = (const float*)d_in[2];
    const float* a_src1 = (const float*)d_in[3];
    const float* a_dst1 = (const float*)d_in[4];
    const float* b1     = (const float*)d_in[5];
    const float* W2     = (const float*)d_in[6];
    const float* a_src2 = (const float*)d_in[7];
    const float* a_dst2 = (const float*)d_in[8];
    const float* b2     = (const float*)d_in[9];
    const float* Wp1    = (const float*)d_in[10];
    const float* bp1    = (const float*)d_in[11];
    const float* Wp2    = (const float*)d_in[12];
    const float* bp2    = (const float*)d_in[13];
    float* outp = (float*)d_out;

    // workspace carve-up (all regions 16B aligned)
    char* w = (char*)d_ws;
    ushort* hbf  = (ushort*)w; w += (size_t)NPAD * 256 * sizeof(ushort);  // 51.2MB (xb first, then h2)
    ushort* obf  = (ushort*)w; w += (size_t)NPAD * 256 * sizeof(ushort);  // 51.2MB (g1; outb2 scratch)
    ushort* W1t  = (ushort*)w; w += (size_t)256 * 128 * sizeof(ushort);
    ushort* W2t  = (ushort*)w; w += (size_t)256 * 256 * sizeof(ushort);
    float2* Wf   = (float2*)w; w += 256 * sizeof(float2);
    float*  bfv  = (float*)w;  w += 4 * sizeof(float);
    float*  va   = (float*)w;  w += 512 * sizeof(float);
    float2* as1  = (float2*)w; w += (size_t)NPAD * sizeof(float2);
    float2* ad1  = (float2*)w; w += (size_t)NPAD * sizeof(float2);
    float2* as2  = (float2*)w; w += (size_t)NPAD * sizeof(float2);
    float2* ad2  = (float2*)w; w += (size_t)NPAD * sizeof(float2);
    int* deg       = (int*)w; w += (size_t)NNODES * sizeof(int);
    int* row_start = (int*)w; w += (size_t)(NNODES + 16) * sizeof(int);
    int* cursor    = (int*)w; w += (size_t)NNODES * sizeof(int);
    int* csr_src   = (int*)w; w += (size_t)ETOT * sizeof(int);
    int* bsum      = (int*)w; w += 512 * sizeof(int);

    const int SCAN_BLOCKS = (NNODES + 255) / 256;   // 391
    const int NODE_WAVES  = (NNODES + 3) / 4;       // 25000
    const int MB = NPAD / 64;                       // 1563

    // --- CSR build + weight prep ---
    hipMemsetAsync(deg, 0, (size_t)NNODES * sizeof(int), stream);
    setup1_kernel<<<HIST_BLOCKS + 386, 256, 0, stream>>>(ei, deg, W1, W1t, W2, W2t,
                                                         Wp1, bp1, Wp2, bp2, Wf, bfv,
                                                         a_src1, a_dst1, va);
    scan1_kernel<<<SCAN_BLOCKS, 256, 0, stream>>>(deg, row_start, bsum);
    scan_fix_kernel<<<SCAN_BLOCKS, 256, 0, stream>>>(row_start, bsum, cursor);

    // --- scatter + alpha_x (independent, merged into one dispatch) ---
    ushort* xb = hbf;   // 25.6MB bf16 x (first half of hbf; dead before h2 write)
    scatter_alpha_kernel<<<ALPHA_BLOCKS + HIST_BLOCKS, 256, 0, stream>>>(
        ei, cursor, csr_src, x, (const float4*)va, (uint*)xb, as1, ad1);

    // --- layer-1 gather in input space (full-occupancy standalone) ---
    gather1_kernel<<<NODE_WAVES, 256, 0, stream>>>((const uint*)xb, row_start, csr_src,
                                                   as1, ad1, obf);

    // --- fused GEMM: g1 -> (relu GEMM1 in LDS) -> GEMM2 -> h2 + logits2 ---
    mfma_gemm_fused<<<MB, 256, 0, stream>>>(obf, W1t, b1, W2t, hbf,
                                            (float*)as2, (float*)ad2, a_src2, a_dst2);

    // --- layer 2 gather fused with post_mp + sigmoid ---
    gather_kernel<<<NODE_WAVES, 256, 0, stream>>>((const uint2*)hbf, row_start, csr_src,
                                                  as2, ad2, (const float4*)b2, (uint2*)obf,
                                                  (const float4*)Wf, bfv, (float2*)outp, 1);
}